// Round 7
// baseline (242.858 us; speedup 1.0000x reference)
//
#include <hip/hip_runtime.h>
#include <hip/hip_bf16.h>

#define F_FIELDS 39
#define VOCAB    100000
#define EMB      16
#define BATCH    16384
#define H1       32
#define H2       32
#define KSTEPS   20   /* K = 640 = 20 x 32 */
#define KPW      5    /* MFMA k-steps per wave (4-way K-split) */
#define REP      8    /* diagnostic repeat to surface this dispatch in rocprof top-5 */

typedef __bf16 bf16x8 __attribute__((ext_vector_type(8)));
typedef float  f32x4  __attribute__((ext_vector_type(4)));

// opaque pointer laundering: compiler cannot CSE loads across reps
__device__ __forceinline__ const float* opqf(const float* p) {
    unsigned long long v = (unsigned long long)p;
    asm volatile("" : "+v"(v));
    return (const float*)v;
}
__device__ __forceinline__ const __bf16* opqb(const __bf16* p) {
    unsigned long long v = (unsigned long long)p;
    asm volatile("" : "+v"(v));
    return (const __bf16*)v;
}

// ---------------- pre-kernel: W1 (f32, [624][32]) -> bf16 MFMA-B fragments in d_ws ----------------
// frag id = (kstep*2 + nhalf)*64 + lane; element j: k = kstep*32 + (lane>>4)*8 + j, n = nhalf*16 + (lane&15)
__global__ __launch_bounds__(256) void swizzle_w1_kernel(const float* __restrict__ W1,
                                                         __bf16* __restrict__ ws)
{
    int fidx = blockIdx.x * 256 + threadIdx.x;
    if (fidx >= KSTEPS * 2 * 64) return;
    int lane = fidx & 63;
    int nh   = (fidx >> 6) & 1;
    int ks   = fidx >> 7;
    int k0   = ks * 32 + (lane >> 4) * 8;
    int n    = nh * 16 + (lane & 15);
    __bf16 vals[8];
    #pragma unroll
    for (int j = 0; j < 8; ++j) {
        int k = k0 + j;
        vals[j] = (k < F_FIELDS * EMB) ? (__bf16)W1[k * H1 + n] : (__bf16)0.0f;
    }
    *reinterpret_cast<bf16x8*>(&ws[fidx * 8]) = *reinterpret_cast<const bf16x8*>(vals);
}

// ---------------- main kernel: EXACT R3 structure, body wrapped in REP loop ----------------
__global__ __launch_bounds__(256, 4) void deepfm_main(
    const int*   __restrict__ Xi,  const float* __restrict__ Xv,
    const float* __restrict__ emb1,const float* __restrict__ emb2,
    const __bf16* __restrict__ wsW1,
    const float* __restrict__ b1,  const float* __restrict__ W2,
    const float* __restrict__ b2,  const float* __restrict__ bias,
    float* __restrict__ out)
{
    __shared__ int   sXi[16 * F_FIELDS];
    __shared__ float sXv[16 * F_FIELDS];
    __shared__ float pacc[4][16][32];
    __shared__ float sbuf[4][16][16];
    __shared__ float qbuf[4][16];
    __shared__ float fbuf[4][16];
    __shared__ float W2s[H1 * H2];
    __shared__ float hs[16][32];

    const int t    = threadIdx.x;
    const int h    = t >> 6;
    const int l    = t & 63;
    const int sloc = l & 15;
    const int q    = l >> 4;
    const int fpar = q >> 1;
    const int eoff = (q & 1) * 8;
    const int blk  = blockIdx.x;

    {
        const int base = blk * 16 * F_FIELDS;
        for (int i = t; i < 16 * F_FIELDS; i += 256) {
            sXi[i] = Xi[base + i];
            sXv[i] = Xv[base + i];
        }
    }
    reinterpret_cast<float4*>(W2s)[t] = reinterpret_cast<const float4*>(W2)[t];
    __syncthreads();

    #pragma unroll 1
    for (int rep = 0; rep < REP; ++rep) {
        const float*  emb2r = opqf(emb2);
        const float*  emb1r = opqf(emb1);
        const bf16x8* wsf   = reinterpret_cast<const bf16x8*>(opqb(wsW1));

        // ---- gather issue: 10 float4 loads per lane ----
        float xvm[KPW];
        float4 g0[KPW], g1[KPW];
        #pragma unroll
        for (int ks = 0; ks < KPW; ++ks) {
            int f = 8 * ks + 2 * h + fpar;
            bool v = (f < F_FIELDS);
            int fi = v ? f : 0;
            int idx = sXi[sloc * F_FIELDS + fi];
            xvm[ks] = v ? sXv[sloc * F_FIELDS + fi] : 0.0f;
            const float4* rp = reinterpret_cast<const float4*>(emb2r + (fi * VOCAB + idx) * EMB + eoff);
            g0[ks] = rp[0];
            g1[ks] = rp[1];
        }
        // first-order gathers
        float e1v[3], xvf[3];
        #pragma unroll
        for (int i = 0; i < 3; ++i) {
            int f = 4 * h + q + 16 * i;
            bool v = (f < F_FIELDS);
            int fi = v ? f : 0;
            int idx = sXi[sloc * F_FIELDS + fi];
            xvf[i] = v ? sXv[sloc * F_FIELDS + fi] : 0.0f;
            e1v[i] = emb1r[fi * VOCAB + idx];
        }

        // ---- consume: FM stats + layer-1 MFMA ----
        f32x4 acc0 = {0.f,0.f,0.f,0.f}, acc1 = {0.f,0.f,0.f,0.f};
        float sa[8];
        float qq = 0.f;
        #pragma unroll
        for (int j = 0; j < 8; ++j) sa[j] = 0.f;

        #pragma unroll
        for (int ks = 0; ks < KPW; ++ks) {
            int kstep = 4 * ks + h;
            bf16x8 fr0 = wsf[(kstep * 2 + 0) * 64 + l];
            bf16x8 fr1 = wsf[(kstep * 2 + 1) * 64 + l];
            float xv = xvm[ks];
            float e[8] = { g0[ks].x*xv, g0[ks].y*xv, g0[ks].z*xv, g0[ks].w*xv,
                           g1[ks].x*xv, g1[ks].y*xv, g1[ks].z*xv, g1[ks].w*xv };
            bf16x8 a;
            #pragma unroll
            for (int j = 0; j < 8; ++j) {
                a[j] = (__bf16)e[j];
                sa[j] += e[j];
                qq   += e[j]*e[j];
            }
            acc0 = __builtin_amdgcn_mfma_f32_16x16x32_bf16(a, fr0, acc0, 0, 0, 0);
            acc1 = __builtin_amdgcn_mfma_f32_16x16x32_bf16(a, fr1, acc1, 0, 0, 0);
        }

        // ---- FM partial reduce within wave ----
        float sf[8];
        #pragma unroll
        for (int j = 0; j < 8; ++j) sf[j] = sa[j] + __shfl_xor(sa[j], 32);
        qq += __shfl_xor(qq, 32);
        qq += __shfl_xor(qq, 16);
        if (q < 2) {
            float4* srow = reinterpret_cast<float4*>(&sbuf[h][sloc][q * 8]);
            srow[0] = make_float4(sf[0], sf[1], sf[2], sf[3]);
            srow[1] = make_float4(sf[4], sf[5], sf[6], sf[7]);
        }
        if (l < 16) qbuf[h][sloc] = qq;

        // ---- first-order partial ----
        float facc = 0.f;
        #pragma unroll
        for (int i = 0; i < 3; ++i) facc += e1v[i] * xvf[i];
        facc += __shfl_xor(facc, 16);
        facc += __shfl_xor(facc, 32);
        if (l < 16) fbuf[h][sloc] = facc;

        // ---- layer-1 partials -> LDS ----
        float badd0 = (h == 0) ? b1[sloc]      : 0.f;
        float badd1 = (h == 0) ? b1[16 + sloc] : 0.f;
        #pragma unroll
        for (int r = 0; r < 4; ++r) {
            int row = q * 4 + r;
            pacc[h][row][sloc]      = acc0[r] + badd0;
            pacc[h][row][16 + sloc] = acc1[r] + badd1;
        }
        __syncthreads();

        // ---- h = relu(sum of partials) ----
        {
            int ss = t >> 4, c = t & 15;
            hs[ss][c]      = fmaxf(pacc[0][ss][c]      + pacc[1][ss][c]      + pacc[2][ss][c]      + pacc[3][ss][c],      0.f);
            hs[ss][c + 16] = fmaxf(pacc[0][ss][c + 16] + pacc[1][ss][c + 16] + pacc[2][ss][c + 16] + pacc[3][ss][c + 16], 0.f);
        }
        __syncthreads();

        // ---- final: 16 threads per sample ----
        const int so = t >> 4;
        const int u  = t & 15;

        float sv = sbuf[0][so][u] + sbuf[1][so][u] + sbuf[2][so][u] + sbuf[3][so][u];
        float s2 = sv * sv;

        float a0 = b2[2 * u], a1 = b2[2 * u + 1];
        #pragma unroll
        for (int i = 0; i < H1; ++i) {
            float hv = hs[so][i];
            a0 += hv * W2s[i * H2 + 2 * u];
            a1 += hv * W2s[i * H2 + 2 * u + 1];
        }
        float psum = fmaxf(a0, 0.f) + fmaxf(a1, 0.f);

        psum += __shfl_xor(psum, 1);  s2 += __shfl_xor(s2, 1);
        psum += __shfl_xor(psum, 2);  s2 += __shfl_xor(s2, 2);
        psum += __shfl_xor(psum, 4);  s2 += __shfl_xor(s2, 4);
        psum += __shfl_xor(psum, 8);  s2 += __shfl_xor(s2, 8);

        if (u == 0) {
            float qtot = qbuf[0][so] + qbuf[1][so] + qbuf[2][so] + qbuf[3][so];
            float ftot = fbuf[0][so] + fbuf[1][so] + fbuf[2][so] + fbuf[3][so];
            out[blk * 16 + so] = psum + 0.5f * (s2 - qtot) + ftot + bias[0];
        }
        __syncthreads();   // protect LDS buffers before next rep overwrites
    }
}

extern "C" void kernel_launch(void* const* d_in, const int* in_sizes, int n_in,
                              void* d_out, int out_size, void* d_ws, size_t ws_size,
                              hipStream_t stream) {
    const int*   Xi   = (const int*)  d_in[0];
    const float* Xv   = (const float*)d_in[1];
    const float* emb1 = (const float*)d_in[2];
    const float* emb2 = (const float*)d_in[3];
    const float* W1   = (const float*)d_in[4];
    const float* b1   = (const float*)d_in[5];
    const float* W2   = (const float*)d_in[6];
    const float* b2   = (const float*)d_in[7];
    const float* bias = (const float*)d_in[8];
    float* out = (float*)d_out;
    __bf16* ws = (__bf16*)d_ws;

    swizzle_w1_kernel<<<(KSTEPS*2*64 + 255)/256, 256, 0, stream>>>(W1, ws);
    deepfm_main<<<BATCH/16, 256, 0, stream>>>(Xi, Xv, emb1, emb2, ws, b1, W2, b2, bias, out);
}

// Round 9
// 89.294 us; speedup vs baseline: 2.7198x; 2.7198x over previous
//
#include <hip/hip_runtime.h>
#include <hip/hip_bf16.h>

#define F_FIELDS 39
#define VOCAB    100000
#define EMB      16
#define BATCH    16384
#define H1       32
#define H2       32
#define KSTEPS   20   /* K = 640 = 20 x 32 */
#define KPW      5    /* MFMA k-steps per wave (4-way K-split) */
#define SPB      8    /* samples per block (occupancy: 2048 blocks = 8 blocks/CU) */

typedef __bf16 bf16x8 __attribute__((ext_vector_type(8)));
typedef float  f32x4  __attribute__((ext_vector_type(4)));

// ---------------- pre-kernel: W1 (f32, [624][32]) -> bf16 MFMA-B fragments in d_ws ----------------
// frag id = (kstep*2 + nhalf)*64 + lane; element j: k = kstep*32 + (lane>>4)*8 + j, n = nhalf*16 + (lane&15)
__global__ __launch_bounds__(256) void swizzle_w1_kernel(const float* __restrict__ W1,
                                                         __bf16* __restrict__ ws)
{
    int fidx = blockIdx.x * 256 + threadIdx.x;
    if (fidx >= KSTEPS * 2 * 64) return;
    int lane = fidx & 63;
    int nh   = (fidx >> 6) & 1;
    int ks   = fidx >> 7;
    int k0   = ks * 32 + (lane >> 4) * 8;
    int n    = nh * 16 + (lane & 15);
    __bf16 vals[8];
    #pragma unroll
    for (int j = 0; j < 8; ++j) {
        int k = k0 + j;
        vals[j] = (k < F_FIELDS * EMB) ? (__bf16)W1[k * H1 + n] : (__bf16)0.0f;
    }
    *reinterpret_cast<bf16x8*>(&ws[fidx * 8]) = *reinterpret_cast<const bf16x8*>(vals);
}

// ---------------- main kernel ----------------
// R3 structure at 8 samples/block (2048 blocks -> 8 blocks/CU -> 32 waves/CU).
// Lanes sloc(=l&15) >= 8 mirror sloc-8 (identical gather addresses dedupe in the coalescer;
// their MFMA C rows 8..15 are duplicates and ignored).
// First-order fields partitioned across waves: wave h, lane (r8,g8): f = 32i + 8h + g8.
__global__ __launch_bounds__(256, 8) void deepfm_main(
    const int*   __restrict__ Xi,  const float* __restrict__ Xv,
    const float* __restrict__ emb1,const float* __restrict__ emb2,
    const __bf16* __restrict__ wsW1,
    const float* __restrict__ b1,  const float* __restrict__ W2,
    const float* __restrict__ b2,  const float* __restrict__ bias,
    float* __restrict__ out)
{
    __shared__ int   sXi[SPB * F_FIELDS];   // 1.25 KB
    __shared__ float sXv[SPB * F_FIELDS];   // 1.25 KB
    __shared__ float pacc[4][SPB][32];      // 4 KB   per-wave layer-1 partials (rows 0..7)
    __shared__ float sbuf[4][SPB][16];      // 2 KB   per-wave FM s-vector partials
    __shared__ float qbuf[4][SPB];          // per-wave FM sq-sum partials
    __shared__ float fbuf[4][SPB];          // per-wave first-order partials
    __shared__ float W2s[H1 * H2];          // 4 KB
    __shared__ float hs[SPB][32];           // 1 KB   relu(layer-1)

    const int t    = threadIdx.x;
    const int h    = t >> 6;           // wave id (K-split)
    const int l    = t & 63;
    const int sloc = l & 15;           // gather/FM: sample slot (>=8 are mirrors); MFMA C: col
    const int r    = sloc & 7;         // real sample index within block
    const int q    = l >> 4;
    const int fpar = q >> 1;
    const int eoff = (q & 1) * 8;
    const int blk  = blockIdx.x;

    // coalesced stage of this block's Xi/Xv rows (8 samples x 39, contiguous)
    {
        const int base = blk * SPB * F_FIELDS;
        for (int i = t; i < SPB * F_FIELDS; i += 256) {
            sXi[i] = Xi[base + i];
            sXv[i] = Xv[base + i];
        }
    }
    reinterpret_cast<float4*>(W2s)[t] = reinterpret_cast<const float4*>(W2)[t];
    __syncthreads();

    // ---- gather issue: 10 float4 loads per lane (lanes sloc>=8 duplicate sloc-8) ----
    float xvm[KPW];
    float4 g0[KPW], g1[KPW];
    #pragma unroll
    for (int ks = 0; ks < KPW; ++ks) {
        int f = 8 * ks + 2 * h + fpar;
        bool v = (f < F_FIELDS);
        int fi = v ? f : 0;
        int idx = sXi[r * F_FIELDS + fi];
        xvm[ks] = v ? sXv[r * F_FIELDS + fi] : 0.0f;
        const float4* rp = reinterpret_cast<const float4*>(emb2 + (fi * VOCAB + idx) * EMB + eoff);
        g0[ks] = rp[0];
        g1[ks] = rp[1];
    }
    // ---- first-order gathers: wave h, lane (r8 = l&7, g8 = l>>3): f = 32i + 8h + g8 ----
    const int r8 = l & 7;
    const int g8 = l >> 3;
    float e1v[2], xvf[2];
    #pragma unroll
    for (int i = 0; i < 2; ++i) {
        int f = 32 * i + 8 * h + g8;
        bool v = (f < F_FIELDS);
        int fi = v ? f : 0;
        int idx = sXi[r8 * F_FIELDS + fi];
        xvf[i] = v ? sXv[r8 * F_FIELDS + fi] : 0.0f;
        e1v[i] = emb1[fi * VOCAB + idx];
    }

    // ---- consume: FM stats + layer-1 MFMA (B-frags from L2) ----
    const bf16x8* wsf = reinterpret_cast<const bf16x8*>(wsW1);
    f32x4 acc0 = {0.f,0.f,0.f,0.f}, acc1 = {0.f,0.f,0.f,0.f};
    float sa[8];
    float qq = 0.f;
    #pragma unroll
    for (int j = 0; j < 8; ++j) sa[j] = 0.f;

    #pragma unroll
    for (int ks = 0; ks < KPW; ++ks) {
        int kstep = 4 * ks + h;
        bf16x8 fr0 = wsf[(kstep * 2 + 0) * 64 + l];
        bf16x8 fr1 = wsf[(kstep * 2 + 1) * 64 + l];
        float xv = xvm[ks];
        float e[8] = { g0[ks].x*xv, g0[ks].y*xv, g0[ks].z*xv, g0[ks].w*xv,
                       g1[ks].x*xv, g1[ks].y*xv, g1[ks].z*xv, g1[ks].w*xv };
        bf16x8 a;
        #pragma unroll
        for (int j = 0; j < 8; ++j) {
            a[j] = (__bf16)e[j];
            sa[j] += e[j];
            qq   += e[j]*e[j];
        }
        acc0 = __builtin_amdgcn_mfma_f32_16x16x32_bf16(a, fr0, acc0, 0, 0, 0);
        acc1 = __builtin_amdgcn_mfma_f32_16x16x32_bf16(a, fr1, acc1, 0, 0, 0);
    }

    // ---- FM partial reduce within wave (combine field parity: lane^32, same eoff) ----
    float sf[8];
    #pragma unroll
    for (int j = 0; j < 8; ++j) sf[j] = sa[j] + __shfl_xor(sa[j], 32);
    qq += __shfl_xor(qq, 32);
    qq += __shfl_xor(qq, 16);
    if (q < 2 && sloc < SPB) {   // q=0 -> positions 0..7, q=1 -> positions 8..15
        float4* srow = reinterpret_cast<float4*>(&sbuf[h][sloc][q * 8]);
        srow[0] = make_float4(sf[0], sf[1], sf[2], sf[3]);
        srow[1] = make_float4(sf[4], sf[5], sf[6], sf[7]);
    }
    if (l < SPB) qbuf[h][l] = qq;

    // ---- first-order partial: reduce across the 8 g8-lanes of each sample ----
    float facc = 0.f;
    #pragma unroll
    for (int i = 0; i < 2; ++i) facc += e1v[i] * xvf[i];
    facc += __shfl_xor(facc, 8);
    facc += __shfl_xor(facc, 16);
    facc += __shfl_xor(facc, 32);
    if (l < SPB) fbuf[h][l] = facc;

    // ---- layer-1 partials -> LDS (rows 0..7 only; b1 folded into wave 0) ----
    if (q < 2) {
        float badd0 = (h == 0) ? b1[sloc]      : 0.f;
        float badd1 = (h == 0) ? b1[16 + sloc] : 0.f;
        #pragma unroll
        for (int rr = 0; rr < 4; ++rr) {
            int row = q * 4 + rr;               // 0..7 = real samples
            pacc[h][row][sloc]      = acc0[rr] + badd0;
            pacc[h][row][16 + sloc] = acc1[rr] + badd1;
        }
    }
    __syncthreads();

    // ---- h = relu(sum of partials): 8x32 = 256 values, 1 per thread ----
    {
        int ss = t >> 5, c = t & 31;
        hs[ss][c] = fmaxf(pacc[0][ss][c] + pacc[1][ss][c] + pacc[2][ss][c] + pacc[3][ss][c], 0.f);
    }
    __syncthreads();

    // ---- final: 32 threads per sample, 1 output col each ----
    const int so = t >> 5;
    const int u  = t & 31;

    float s2 = 0.f;
    if (u < 16) {
        float sv = sbuf[0][so][u] + sbuf[1][so][u] + sbuf[2][so][u] + sbuf[3][so][u];
        s2 = sv * sv;
    }

    float a0 = b2[u];
    #pragma unroll
    for (int i = 0; i < H1; ++i) {
        a0 += hs[so][i] * W2s[i * H2 + u];
    }
    float psum = fmaxf(a0, 0.f);

    psum += __shfl_xor(psum, 1);  s2 += __shfl_xor(s2, 1);
    psum += __shfl_xor(psum, 2);  s2 += __shfl_xor(s2, 2);
    psum += __shfl_xor(psum, 4);  s2 += __shfl_xor(s2, 4);
    psum += __shfl_xor(psum, 8);  s2 += __shfl_xor(s2, 8);
    psum += __shfl_xor(psum, 16); s2 += __shfl_xor(s2, 16);

    if (u == 0) {
        float qtot = qbuf[0][so] + qbuf[1][so] + qbuf[2][so] + qbuf[3][so];
        float ftot = fbuf[0][so] + fbuf[1][so] + fbuf[2][so] + fbuf[3][so];
        out[blk * SPB + so] = psum + 0.5f * (s2 - qtot) + ftot + bias[0];
    }
}

extern "C" void kernel_launch(void* const* d_in, const int* in_sizes, int n_in,
                              void* d_out, int out_size, void* d_ws, size_t ws_size,
                              hipStream_t stream) {
    const int*   Xi   = (const int*)  d_in[0];
    const float* Xv   = (const float*)d_in[1];
    const float* emb1 = (const float*)d_in[2];
    const float* emb2 = (const float*)d_in[3];
    const float* W1   = (const float*)d_in[4];
    const float* b1   = (const float*)d_in[5];
    const float* W2   = (const float*)d_in[6];
    const float* b2   = (const float*)d_in[7];
    const float* bias = (const float*)d_in[8];
    float* out = (float*)d_out;
    __bf16* ws = (__bf16*)d_ws;

    swizzle_w1_kernel<<<(KSTEPS*2*64 + 255)/256, 256, 0, stream>>>(W1, ws);
    deepfm_main<<<BATCH/SPB, 256, 0, stream>>>(Xi, Xv, emb1, emb2, ws, b1, W2, b2, bias, out);
}

// Round 10
// 37.484 us; speedup vs baseline: 6.4790x; 2.3822x over previous
//
#include <hip/hip_runtime.h>
#include <hip/hip_bf16.h>

#define F_FIELDS 39
#define VOCAB    100000
#define EMB      16
#define BATCH    16384
#define H1       32
#define H2       32
#define KSTEPS   20   /* K = 640 = 20 x 32 */
#define KPW      5    /* MFMA k-steps per wave (4-way K-split) */

// d_ws byte layout:
//   [0,        2555904)  ws1e  float[39*16384]  raw emb1 gathers, field-major
//   [2555904,  5111808)  XiT   int[39*16384]    transposed indices
//   [5111808,  5152768)  frags bf16[2560*8]     W1 MFMA-B fragments
#define WS1E_OFF  0
#define XIT_OFF   2555904
#define FRAG_OFF  5111808

typedef __bf16 bf16x8 __attribute__((ext_vector_type(8)));
typedef float  f32x4  __attribute__((ext_vector_type(4)));

// ---------------- W1 (f32, [624][32]) -> bf16 MFMA-B fragments ----------------
// frag id = (kstep*2 + nhalf)*64 + lane; elem j: k = kstep*32 + (lane>>4)*8 + j, n = nhalf*16 + (lane&15)
__global__ __launch_bounds__(256) void swizzle_w1_kernel(const float* __restrict__ W1,
                                                         __bf16* __restrict__ ws)
{
    int fidx = blockIdx.x * 256 + threadIdx.x;
    if (fidx >= KSTEPS * 2 * 64) return;
    int lane = fidx & 63;
    int nh   = (fidx >> 6) & 1;
    int ks   = fidx >> 7;
    int k0   = ks * 32 + (lane >> 4) * 8;
    int n    = nh * 16 + (lane & 15);
    __bf16 vals[8];
    #pragma unroll
    for (int j = 0; j < 8; ++j) {
        int k = k0 + j;
        vals[j] = (k < F_FIELDS * EMB) ? (__bf16)W1[k * H1 + n] : (__bf16)0.0f;
    }
    *reinterpret_cast<bf16x8*>(&ws[fidx * 8]) = *reinterpret_cast<const bf16x8*>(vals);
}

// ---------------- Xi transpose: [16384][39] -> [39][16384], fully coalesced ----------------
__global__ __launch_bounds__(256) void xi_transpose_kernel(const int* __restrict__ Xi,
                                                           int* __restrict__ XiT)
{
    __shared__ int tile[F_FIELDS][65];   // +1 pad: conflict-free scattered writes
    const int blk = blockIdx.x;          // 256 blocks x 64 samples
    const int t   = threadIdx.x;
    const int base = blk * 64 * F_FIELDS;
    for (int i = t; i < 64 * F_FIELDS; i += 256) {
        int s = i / F_FIELDS, f = i % F_FIELDS;   // compiler magic-mul
        tile[f][s] = Xi[base + i];
    }
    __syncthreads();
    for (int j = t; j < 64 * F_FIELDS; j += 256) {
        int f = j >> 6, s = j & 63;               // j < 2496 -> f <= 38
        XiT[f * BATCH + blk * 64 + s] = tile[f][s];
    }
}

// ---------------- emb1 prep: field-clustered, XCD-pinned ----------------
// Grid 1280: xcd = b&7 (round-robin dispatch), sgrp = b>>3, field = (b&7) + 8*(sgrp>>5),
// chunk = sgrp&31.  Field f's 32 chunk-blocks all land on XCD f%8 -> its 400 KB emb1
// slice is L2-resident on exactly one XCD.  ws1e[f][b] = emb1[f, Xi[b,f]]  (Xv applied in main).
__global__ __launch_bounds__(256) void emb1_prep_kernel(const int* __restrict__ XiT,
                                                        const float* __restrict__ emb1,
                                                        float* __restrict__ ws1e)
{
    const int b     = blockIdx.x;
    const int sgrp  = b >> 3;
    const int field = (b & 7) + 8 * (sgrp >> 5);
    if (field >= F_FIELDS) return;
    const int chunk = sgrp & 31;
    const int g = chunk * 512 + threadIdx.x * 2;
    int2 idx = *reinterpret_cast<const int2*>(&XiT[field * BATCH + g]);
    const float* eb = emb1 + (size_t)field * VOCAB;
    float2 o;
    o.x = eb[idx.x];
    o.y = eb[idx.y];
    *reinterpret_cast<float2*>(&ws1e[field * BATCH + g]) = o;
}

// ---------------- main kernel (R3 structure, emb1 gathers removed) ----------------
// Block = 256 threads = 4 waves = 16 samples; K split 4-way by wave.
// Lane map: sample = lane&15; q = lane>>4; fpar = q>>1; eoff = (q&1)*8.
//   field f = 8*ks' + 2*h + fpar  (f == 39 masked via xv=0)
// A-frag: row = lane&15, k_local = q*8+j.   C-frag: row = q*4+reg, col = lane&15.
__global__ __launch_bounds__(256, 4) void deepfm_main(
    const int*   __restrict__ Xi,  const float* __restrict__ Xv,
    const float* __restrict__ emb2,
    const __bf16* __restrict__ wsW1, const float* __restrict__ ws1e,
    const float* __restrict__ b1,  const float* __restrict__ W2,
    const float* __restrict__ b2,  const float* __restrict__ bias,
    float* __restrict__ out)
{
    __shared__ int   sXi[16 * F_FIELDS];   // 2.4 KB
    __shared__ float sXv[16 * F_FIELDS];   // 2.4 KB
    __shared__ float pacc[4][16][32];      // 8 KB   per-wave layer-1 partials
    __shared__ float sbuf[4][16][16];      // 4 KB   per-wave FM s-vector partials
    __shared__ float qbuf[4][16];          // per-wave FM sq-sum partials
    __shared__ float W2s[H1 * H2];         // 4 KB
    __shared__ float hs[16][32];           // 2 KB   relu(layer-1)

    const int t    = threadIdx.x;
    const int h    = t >> 6;
    const int l    = t & 63;
    const int sloc = l & 15;
    const int q    = l >> 4;
    const int fpar = q >> 1;
    const int eoff = (q & 1) * 8;
    const int blk  = blockIdx.x;

    // coalesced stage of this block's Xi/Xv rows
    {
        const int base = blk * 16 * F_FIELDS;
        for (int i = t; i < 16 * F_FIELDS; i += 256) {
            sXi[i] = Xi[base + i];
            sXv[i] = Xv[base + i];
        }
    }
    reinterpret_cast<float4*>(W2s)[t] = reinterpret_cast<const float4*>(W2)[t];
    __syncthreads();

    // ---- gather issue: 10 float4 loads per lane ----
    float xvm[KPW];
    float4 g0[KPW], g1[KPW];
    #pragma unroll
    for (int ks = 0; ks < KPW; ++ks) {
        int f = 8 * ks + 2 * h + fpar;
        bool v = (f < F_FIELDS);
        int fi = v ? f : 0;
        int idx = sXi[sloc * F_FIELDS + fi];
        xvm[ks] = v ? sXv[sloc * F_FIELDS + fi] : 0.0f;
        const float4* rp = reinterpret_cast<const float4*>(emb2 + (fi * VOCAB + idx) * EMB + eoff);
        g0[ks] = rp[0];
        g1[ks] = rp[1];
    }

    // ---- consume: FM stats + layer-1 MFMA (B-frags from L2) ----
    const bf16x8* wsf = reinterpret_cast<const bf16x8*>(wsW1);
    f32x4 acc0 = {0.f,0.f,0.f,0.f}, acc1 = {0.f,0.f,0.f,0.f};
    float sa[8];
    float qq = 0.f;
    #pragma unroll
    for (int j = 0; j < 8; ++j) sa[j] = 0.f;

    #pragma unroll
    for (int ks = 0; ks < KPW; ++ks) {
        int kstep = 4 * ks + h;
        bf16x8 fr0 = wsf[(kstep * 2 + 0) * 64 + l];
        bf16x8 fr1 = wsf[(kstep * 2 + 1) * 64 + l];
        float xv = xvm[ks];
        float e[8] = { g0[ks].x*xv, g0[ks].y*xv, g0[ks].z*xv, g0[ks].w*xv,
                       g1[ks].x*xv, g1[ks].y*xv, g1[ks].z*xv, g1[ks].w*xv };
        bf16x8 a;
        #pragma unroll
        for (int j = 0; j < 8; ++j) {
            a[j] = (__bf16)e[j];
            sa[j] += e[j];
            qq   += e[j]*e[j];
        }
        acc0 = __builtin_amdgcn_mfma_f32_16x16x32_bf16(a, fr0, acc0, 0, 0, 0);
        acc1 = __builtin_amdgcn_mfma_f32_16x16x32_bf16(a, fr1, acc1, 0, 0, 0);
    }

    // ---- FM partial reduce within wave (combine field parity: lane^32, same eoff) ----
    float sf[8];
    #pragma unroll
    for (int j = 0; j < 8; ++j) sf[j] = sa[j] + __shfl_xor(sa[j], 32);
    qq += __shfl_xor(qq, 32);
    qq += __shfl_xor(qq, 16);
    if (q < 2) {   // q=0 -> positions 0..7, q=1 -> positions 8..15
        float4* srow = reinterpret_cast<float4*>(&sbuf[h][sloc][q * 8]);
        srow[0] = make_float4(sf[0], sf[1], sf[2], sf[3]);
        srow[1] = make_float4(sf[4], sf[5], sf[6], sf[7]);
    }
    if (l < 16) qbuf[h][sloc] = qq;

    // ---- layer-1 partials -> LDS (b1 folded into wave 0) ----
    float badd0 = (h == 0) ? b1[sloc]      : 0.f;
    float badd1 = (h == 0) ? b1[16 + sloc] : 0.f;
    #pragma unroll
    for (int r = 0; r < 4; ++r) {
        int row = q * 4 + r;
        pacc[h][row][sloc]      = acc0[r] + badd0;
        pacc[h][row][16 + sloc] = acc1[r] + badd1;
    }
    __syncthreads();

    // ---- h = relu(sum of partials) ----
    {
        int ss = t >> 4, c = t & 15;
        hs[ss][c]      = fmaxf(pacc[0][ss][c]      + pacc[1][ss][c]      + pacc[2][ss][c]      + pacc[3][ss][c],      0.f);
        hs[ss][c + 16] = fmaxf(pacc[0][ss][c + 16] + pacc[1][ss][c + 16] + pacc[2][ss][c + 16] + pacc[3][ss][c + 16], 0.f);
    }
    __syncthreads();

    // ---- final: 16 threads per sample ----
    const int so = t >> 4;
    const int u  = t & 15;
    const int sg = blk * 16 + so;

    float sv = sbuf[0][so][u] + sbuf[1][so][u] + sbuf[2][so][u] + sbuf[3][so][u];
    float s2 = sv * sv;

    // first-order: raw emb1 gathers from ws1e (field-major; 39 cache lines per block), x Xv here
    float fo = ws1e[u * BATCH + sg]        * sXv[so * F_FIELDS + u]
             + ws1e[(u + 16) * BATCH + sg] * sXv[so * F_FIELDS + u + 16];
    if (u < 7)
        fo += ws1e[(u + 32) * BATCH + sg] * sXv[so * F_FIELDS + u + 32];

    float a0 = b2[2 * u], a1 = b2[2 * u + 1];
    #pragma unroll
    for (int i = 0; i < H1; ++i) {
        float hv = hs[so][i];
        a0 += hv * W2s[i * H2 + 2 * u];
        a1 += hv * W2s[i * H2 + 2 * u + 1];
    }
    float psum = fmaxf(a0, 0.f) + fmaxf(a1, 0.f) + fo;

    psum += __shfl_xor(psum, 1);  s2 += __shfl_xor(s2, 1);
    psum += __shfl_xor(psum, 2);  s2 += __shfl_xor(s2, 2);
    psum += __shfl_xor(psum, 4);  s2 += __shfl_xor(s2, 4);
    psum += __shfl_xor(psum, 8);  s2 += __shfl_xor(s2, 8);

    if (u == 0) {
        float qtot = qbuf[0][so] + qbuf[1][so] + qbuf[2][so] + qbuf[3][so];
        out[sg] = psum + 0.5f * (s2 - qtot) + bias[0];
    }
}

extern "C" void kernel_launch(void* const* d_in, const int* in_sizes, int n_in,
                              void* d_out, int out_size, void* d_ws, size_t ws_size,
                              hipStream_t stream) {
    const int*   Xi   = (const int*)  d_in[0];
    const float* Xv   = (const float*)d_in[1];
    const float* emb1 = (const float*)d_in[2];
    const float* emb2 = (const float*)d_in[3];
    const float* W1   = (const float*)d_in[4];
    const float* b1   = (const float*)d_in[5];
    const float* W2   = (const float*)d_in[6];
    const float* b2   = (const float*)d_in[7];
    const float* bias = (const float*)d_in[8];
    float* out = (float*)d_out;

    char* wsb = (char*)d_ws;
    float*  ws1e   = (float*)(wsb + WS1E_OFF);
    int*    XiT    = (int*)  (wsb + XIT_OFF);
    __bf16* wsfrag = (__bf16*)(wsb + FRAG_OFF);

    swizzle_w1_kernel<<<(KSTEPS*2*64 + 255)/256, 256, 0, stream>>>(W1, wsfrag);
    xi_transpose_kernel<<<BATCH/64, 256, 0, stream>>>(Xi, XiT);
    emb1_prep_kernel<<<1280, 256, 0, stream>>>(XiT, emb1, ws1e);
    deepfm_main<<<BATCH/16, 256, 0, stream>>>(Xi, Xv, emb2, wsfrag, ws1e, b1, W2, b2, bias, out);
}

// Round 11
// 35.003 us; speedup vs baseline: 6.9383x; 1.0709x over previous
//
#include <hip/hip_runtime.h>
#include <hip/hip_bf16.h>

#define F_FIELDS 39
#define VOCAB    100000
#define EMB      16
#define BATCH    16384
#define H1       32
#define H2       32
#define KSTEPS   20   /* K = 640 = 20 x 32 */
#define KPW      5    /* MFMA k-steps per wave (4-way K-split) */

typedef __bf16 bf16x8 __attribute__((ext_vector_type(8)));
typedef float  f32x4  __attribute__((ext_vector_type(4)));

// ---------------- pre-kernel: W1 (f32, [624][32]) -> bf16 MFMA-B fragments in d_ws ----------------
// frag id = (kstep*2 + nhalf)*64 + lane; element j: k = kstep*32 + (lane>>4)*8 + j, n = nhalf*16 + (lane&15)
__global__ __launch_bounds__(256) void swizzle_w1_kernel(const float* __restrict__ W1,
                                                         __bf16* __restrict__ ws)
{
    int fidx = blockIdx.x * 256 + threadIdx.x;
    if (fidx >= KSTEPS * 2 * 64) return;
    int lane = fidx & 63;
    int nh   = (fidx >> 6) & 1;
    int ks   = fidx >> 7;
    int k0   = ks * 32 + (lane >> 4) * 8;
    int n    = nh * 16 + (lane & 15);
    __bf16 vals[8];
    #pragma unroll
    for (int j = 0; j < 8; ++j) {
        int k = k0 + j;
        vals[j] = (k < F_FIELDS * EMB) ? (__bf16)W1[k * H1 + n] : (__bf16)0.0f;
    }
    *reinterpret_cast<bf16x8*>(&ws[fidx * 8]) = *reinterpret_cast<const bf16x8*>(vals);
}

// ---------------- main kernel ----------------
// Block = 256 threads = 4 waves = one group of 16 samples; K split 4-way by wave.
// Wave h owns ksteps = 4*ks'+h. Lane map: sample = lane&15; q = lane>>4; fpar = q>>1; eoff = (q&1)*8.
//   field f = 8*ks' + 2*h + fpar  (f == 39 masked via xv=0)
// A-frag: row = lane&15, k_local = q*8+j.   C-frag: row = q*4+reg, col = lane&15.
__global__ __launch_bounds__(256, 4) void deepfm_main(
    const int*   __restrict__ Xi,  const float* __restrict__ Xv,
    const float* __restrict__ emb1,const float* __restrict__ emb2,
    const __bf16* __restrict__ wsW1,
    const float* __restrict__ b1,  const float* __restrict__ W2,
    const float* __restrict__ b2,  const float* __restrict__ bias,
    float* __restrict__ out)
{
    __shared__ int   sXi[16 * F_FIELDS];   // 2.4 KB
    __shared__ float sXv[16 * F_FIELDS];   // 2.4 KB
    __shared__ float pacc[4][16][32];      // 8 KB   per-wave layer-1 partials
    __shared__ float sbuf[4][16][16];      // 4 KB   per-wave FM s-vector partials
    __shared__ float qbuf[4][16];          // per-wave FM sq-sum partials
    __shared__ float fbuf[4][16];          // per-wave first-order partials
    __shared__ float W2s[H1 * H2];         // 4 KB
    __shared__ float hs[16][32];           // 2 KB   relu(layer-1)

    const int t    = threadIdx.x;
    const int h    = t >> 6;
    const int l    = t & 63;
    const int sloc = l & 15;
    const int q    = l >> 4;
    const int fpar = q >> 1;
    const int eoff = (q & 1) * 8;
    const int blk  = blockIdx.x;

    // coalesced stage of this block's Xi/Xv rows
    {
        const int base = blk * 16 * F_FIELDS;
        for (int i = t; i < 16 * F_FIELDS; i += 256) {
            sXi[i] = Xi[base + i];
            sXv[i] = Xv[base + i];
        }
    }
    reinterpret_cast<float4*>(W2s)[t] = reinterpret_cast<const float4*>(W2)[t];
    __syncthreads();

    // ---- gather issue: 10 float4 loads per lane ----
    float xvm[KPW];
    float4 g0[KPW], g1[KPW];
    #pragma unroll
    for (int ks = 0; ks < KPW; ++ks) {
        int f = 8 * ks + 2 * h + fpar;
        bool v = (f < F_FIELDS);
        int fi = v ? f : 0;
        int idx = sXi[sloc * F_FIELDS + fi];
        xvm[ks] = v ? sXv[sloc * F_FIELDS + fi] : 0.0f;
        const float4* rp = reinterpret_cast<const float4*>(emb2 + (fi * VOCAB + idx) * EMB + eoff);
        g0[ks] = rp[0];
        g1[ks] = rp[1];
    }
    // first-order gathers: fields f = (4h+q) + 16*i
    float e1v[3], xvf[3];
    #pragma unroll
    for (int i = 0; i < 3; ++i) {
        int f = 4 * h + q + 16 * i;
        bool v = (f < F_FIELDS);
        int fi = v ? f : 0;
        int idx = sXi[sloc * F_FIELDS + fi];
        xvf[i] = v ? sXv[sloc * F_FIELDS + fi] : 0.0f;
        e1v[i] = emb1[fi * VOCAB + idx];
    }

    // ---- consume: FM stats + layer-1 MFMA (B-frags from L2) ----
    const bf16x8* wsf = reinterpret_cast<const bf16x8*>(wsW1);
    f32x4 acc0 = {0.f,0.f,0.f,0.f}, acc1 = {0.f,0.f,0.f,0.f};
    float sa[8];
    float qq = 0.f;
    #pragma unroll
    for (int j = 0; j < 8; ++j) sa[j] = 0.f;

    #pragma unroll
    for (int ks = 0; ks < KPW; ++ks) {
        int kstep = 4 * ks + h;
        bf16x8 fr0 = wsf[(kstep * 2 + 0) * 64 + l];
        bf16x8 fr1 = wsf[(kstep * 2 + 1) * 64 + l];
        float xv = xvm[ks];
        float e[8] = { g0[ks].x*xv, g0[ks].y*xv, g0[ks].z*xv, g0[ks].w*xv,
                       g1[ks].x*xv, g1[ks].y*xv, g1[ks].z*xv, g1[ks].w*xv };
        bf16x8 a;
        #pragma unroll
        for (int j = 0; j < 8; ++j) {
            a[j] = (__bf16)e[j];
            sa[j] += e[j];
            qq   += e[j]*e[j];
        }
        acc0 = __builtin_amdgcn_mfma_f32_16x16x32_bf16(a, fr0, acc0, 0, 0, 0);
        acc1 = __builtin_amdgcn_mfma_f32_16x16x32_bf16(a, fr1, acc1, 0, 0, 0);
    }

    // ---- FM partial reduce within wave (combine field parity: lane^32, same eoff) ----
    float sf[8];
    #pragma unroll
    for (int j = 0; j < 8; ++j) sf[j] = sa[j] + __shfl_xor(sa[j], 32);
    qq += __shfl_xor(qq, 32);
    qq += __shfl_xor(qq, 16);
    if (q < 2) {   // q=0 -> positions 0..7, q=1 -> positions 8..15
        float4* srow = reinterpret_cast<float4*>(&sbuf[h][sloc][q * 8]);
        srow[0] = make_float4(sf[0], sf[1], sf[2], sf[3]);
        srow[1] = make_float4(sf[4], sf[5], sf[6], sf[7]);
    }
    if (l < 16) qbuf[h][sloc] = qq;

    // ---- first-order partial ----
    float facc = 0.f;
    #pragma unroll
    for (int i = 0; i < 3; ++i) facc += e1v[i] * xvf[i];
    facc += __shfl_xor(facc, 16);
    facc += __shfl_xor(facc, 32);
    if (l < 16) fbuf[h][sloc] = facc;

    // ---- layer-1 partials -> LDS (b1 folded into wave 0) ----
    float badd0 = (h == 0) ? b1[sloc]      : 0.f;
    float badd1 = (h == 0) ? b1[16 + sloc] : 0.f;
    #pragma unroll
    for (int r = 0; r < 4; ++r) {
        int row = q * 4 + r;
        pacc[h][row][sloc]      = acc0[r] + badd0;
        pacc[h][row][16 + sloc] = acc1[r] + badd1;
    }
    __syncthreads();

    // ---- h = relu(sum of partials) ----
    {
        int ss = t >> 4, c = t & 15;
        hs[ss][c]      = fmaxf(pacc[0][ss][c]      + pacc[1][ss][c]      + pacc[2][ss][c]      + pacc[3][ss][c],      0.f);
        hs[ss][c + 16] = fmaxf(pacc[0][ss][c + 16] + pacc[1][ss][c + 16] + pacc[2][ss][c + 16] + pacc[3][ss][c + 16], 0.f);
    }
    __syncthreads();

    // ---- final: 16 threads per sample ----
    const int so = t >> 4;
    const int u  = t & 15;

    float sv = sbuf[0][so][u] + sbuf[1][so][u] + sbuf[2][so][u] + sbuf[3][so][u];
    float s2 = sv * sv;

    float a0 = b2[2 * u], a1 = b2[2 * u + 1];
    #pragma unroll
    for (int i = 0; i < H1; ++i) {
        float hv = hs[so][i];
        a0 += hv * W2s[i * H2 + 2 * u];
        a1 += hv * W2s[i * H2 + 2 * u + 1];
    }
    float psum = fmaxf(a0, 0.f) + fmaxf(a1, 0.f);

    psum += __shfl_xor(psum, 1);  s2 += __shfl_xor(s2, 1);
    psum += __shfl_xor(psum, 2);  s2 += __shfl_xor(s2, 2);
    psum += __shfl_xor(psum, 4);  s2 += __shfl_xor(s2, 4);
    psum += __shfl_xor(psum, 8);  s2 += __shfl_xor(s2, 8);

    if (u == 0) {
        float qtot = qbuf[0][so] + qbuf[1][so] + qbuf[2][so] + qbuf[3][so];
        float ftot = fbuf[0][so] + fbuf[1][so] + fbuf[2][so] + fbuf[3][so];
        out[blk * 16 + so] = psum + 0.5f * (s2 - qtot) + ftot + bias[0];
    }
}

extern "C" void kernel_launch(void* const* d_in, const int* in_sizes, int n_in,
                              void* d_out, int out_size, void* d_ws, size_t ws_size,
                              hipStream_t stream) {
    const int*   Xi   = (const int*)  d_in[0];
    const float* Xv   = (const float*)d_in[1];
    const float* emb1 = (const float*)d_in[2];
    const float* emb2 = (const float*)d_in[3];
    const float* W1   = (const float*)d_in[4];
    const float* b1   = (const float*)d_in[5];
    const float* W2   = (const float*)d_in[6];
    const float* b2   = (const float*)d_in[7];
    const float* bias = (const float*)d_in[8];
    float* out = (float*)d_out;
    __bf16* ws = (__bf16*)d_ws;

    swizzle_w1_kernel<<<(KSTEPS*2*64 + 255)/256, 256, 0, stream>>>(W1, ws);
    deepfm_main<<<BATCH/16, 256, 0, stream>>>(Xi, Xv, emb1, emb2, ws, b1, W2, b2, bias, out);
}